// Round 1
// baseline (474.345 us; speedup 1.0000x reference)
//
#include <hip/hip_runtime.h>
#include <hip/hip_bf16.h>
#include <stdint.h>

#define D 128

using bf16x8 = __attribute__((ext_vector_type(8))) short;
using f32x4  = __attribute__((ext_vector_type(4))) float;

__device__ __forceinline__ unsigned short f2bf(float f) {
    unsigned u = __float_as_uint(f);
    u = (u + 0x7fffu + ((u >> 16) & 1u)) >> 16;   // RNE
    return (unsigned short)u;
}
__device__ __forceinline__ float bf2f(unsigned short h) {
    return __uint_as_float(((unsigned)h) << 16);
}

// LDS bf16 row stride: 128 + 8 pad = 136 elems (272 B; 16B-aligned, spreads banks)
#define LSTR 136

// Phase 1: H[r][n][c] (bf16) = sum_k feat[n][k] * W[r][k][c]
// block = 256 thr (4 waves), handles 64 nodes x 1 relation x 128 out-cols.
__global__ __launch_bounds__(256) void transform_kernel(
    const float* __restrict__ feat, const float* __restrict__ W,
    unsigned short* __restrict__ H, int N)
{
    __shared__ unsigned short sm[64 * LSTR + 128 * LSTR];  // A tile + Wt tile (~52 KB)
    const int WBASE = 64 * LSTR;
    const int tile0 = blockIdx.x * 64;
    const int rel   = blockIdx.y;
    const int tid   = threadIdx.x;

    // Stage A = bf16(feat[tile0 .. tile0+63][:]) into padded LDS
    const float4* feat4 = (const float4*)feat;
    #pragma unroll
    for (int i = 0; i < 8; ++i) {
        int idx = tid + 256 * i;          // 0..2047
        int row = idx >> 5, c4 = idx & 31;
        int node = tile0 + row;
        float4 v = make_float4(0.f, 0.f, 0.f, 0.f);
        if (node < N) v = feat4[(size_t)node * 32 + c4];
        ushort4 h;
        h.x = f2bf(v.x); h.y = f2bf(v.y); h.z = f2bf(v.z); h.w = f2bf(v.w);
        *(ushort4*)&sm[row * LSTR + c4 * 4] = h;
    }
    // Stage Wt[c][k] = bf16(W[rel][k][c]) (transposed so B-frag is a b128 read)
    const float4* W4 = (const float4*)(W + (size_t)rel * D * D);
    #pragma unroll
    for (int i = 0; i < 16; ++i) {
        int idx = tid + 256 * i;          // 0..4095
        int k = idx >> 5, c4 = idx & 31;
        float4 v = W4[idx];
        sm[WBASE + (c4 * 4 + 0) * LSTR + k] = f2bf(v.x);
        sm[WBASE + (c4 * 4 + 1) * LSTR + k] = f2bf(v.y);
        sm[WBASE + (c4 * 4 + 2) * LSTR + k] = f2bf(v.z);
        sm[WBASE + (c4 * 4 + 3) * LSTR + k] = f2bf(v.w);
    }
    __syncthreads();

    const int wave = tid >> 6, lane = tid & 63;
    const int q = lane >> 4, mlo = lane & 15;

    // A fragments: A[m=lane&15][k=32*ks + 8*q + j], j=0..7 -> contiguous 16B
    const int arow = wave * 16 + mlo;
    bf16x8 a[4];
    #pragma unroll
    for (int ks = 0; ks < 4; ++ks)
        a[ks] = *(const bf16x8*)&sm[arow * LSTR + ks * 32 + q * 8];

    const size_t Hbase = (size_t)rel * N * D;
    #pragma unroll
    for (int ct = 0; ct < 8; ++ct) {
        f32x4 acc = {0.f, 0.f, 0.f, 0.f};
        const int col = ct * 16 + mlo;
        #pragma unroll
        for (int ks = 0; ks < 4; ++ks) {
            // B[k][n]: n=lane&15, k=32*ks+8*q+j  (from transposed LDS -> b128)
            bf16x8 b = *(const bf16x8*)&sm[WBASE + col * LSTR + ks * 32 + q * 8];
            acc = __builtin_amdgcn_mfma_f32_16x16x32_bf16(a[ks], b, acc, 0, 0, 0);
        }
        // C/D: col = lane&15 (+16*ct), row = (lane>>4)*4 + reg
        const int nb = tile0 + wave * 16 + q * 4;
        #pragma unroll
        for (int r = 0; r < 4; ++r) {
            int node = nb + r;
            if (node < N) H[Hbase + (size_t)node * D + col] = f2bf(acc[r]);
        }
    }
}

// out = feat (float4 copy)
__global__ __launch_bounds__(256) void init_kernel(
    const float* __restrict__ feat, float* __restrict__ out, int n4)
{
    int i = blockIdx.x * 256 + threadIdx.x;
    if (i < n4) ((float4*)out)[i] = ((const float4*)feat)[i];
}

// Phase 2: out[dst] += H[etype][src]   (128 threads per edge, wave-uniform edge)
__global__ __launch_bounds__(256) void scatter_kernel(
    const unsigned short* __restrict__ H, const int* __restrict__ et,
    const int* __restrict__ src, const int* __restrict__ dst,
    float* __restrict__ out, int E, int N)
{
    long long idx = (long long)blockIdx.x * 256 + threadIdx.x;
    int e = (int)(idx >> 7);
    int c = (int)(idx & 127);
    if (e >= E) return;
    e = __builtin_amdgcn_readfirstlane(e);   // wave-uniform -> scalar loads below
    int r = et[e], s = src[e], d = dst[e];
    float m = bf2f(H[((size_t)r * N + s) * D + c]);
    atomicAdd(out + (size_t)d * D + c, m);
}

// Fallback (workspace too small for H): per-edge matvec in fp32 + atomics.
__global__ __launch_bounds__(128) void edge_matvec_kernel(
    const float* __restrict__ feat, const float* __restrict__ W,
    const int* __restrict__ et, const int* __restrict__ src,
    const int* __restrict__ dst, float* __restrict__ out, int E)
{
    __shared__ float xs[D];
    int e = blockIdx.x;
    int c = threadIdx.x;
    int s = src[e], r = et[e], d = dst[e];
    xs[c] = feat[(size_t)s * D + c];
    __syncthreads();
    const float* Wr = W + (size_t)r * D * D;
    float acc = 0.f;
    #pragma unroll 8
    for (int k = 0; k < D; ++k) acc += xs[k] * Wr[(size_t)k * D + c];
    atomicAdd(out + (size_t)d * D + c, acc);
}

extern "C" void kernel_launch(void* const* d_in, const int* in_sizes, int n_in,
                              void* d_out, int out_size, void* d_ws, size_t ws_size,
                              hipStream_t stream) {
    const float* feat = (const float*)d_in[0];
    const float* W    = (const float*)d_in[1];
    const int*   et   = (const int*)d_in[2];
    const int*   src  = (const int*)d_in[3];
    const int*   dst  = (const int*)d_in[4];
    float* out = (float*)d_out;

    const int N = in_sizes[0] / D;
    const int R = in_sizes[1] / (D * D);
    const int E = in_sizes[2];

    // out = feat
    int n4 = (N * D) / 4;
    init_kernel<<<(n4 + 255) / 256, 256, 0, stream>>>(feat, out, n4);

    size_t hbytes = (size_t)R * N * D * sizeof(unsigned short);
    if (ws_size >= hbytes) {
        unsigned short* H = (unsigned short*)d_ws;
        dim3 g((N + 63) / 64, R);
        transform_kernel<<<g, 256, 0, stream>>>(feat, W, H, N);
        long long tot = (long long)E * D;
        int nb = (int)((tot + 255) / 256);
        scatter_kernel<<<nb, 256, 0, stream>>>(H, et, src, dst, out, E, N);
    } else {
        edge_matvec_kernel<<<E, 128, 0, stream>>>(feat, W, et, src, dst, out, E);
    }
}

// Round 2
// 248.828 us; speedup vs baseline: 1.9063x; 1.9063x over previous
//
#include <hip/hip_runtime.h>
#include <hip/hip_bf16.h>
#include <stdint.h>

#define D 128
#define LSTR 136   // bf16 LDS row stride: 128 + 8 pad (272 B, 16B-aligned)

using bf16x8 = __attribute__((ext_vector_type(8))) short;
using f32x4  = __attribute__((ext_vector_type(4))) float;

__device__ __forceinline__ unsigned short f2bf(float f) {
    unsigned u = __float_as_uint(f);
    u = (u + 0x7fffu + ((u >> 16) & 1u)) >> 16;   // RNE
    return (unsigned short)u;
}
__device__ __forceinline__ float bf2f(unsigned short h) {
    return __uint_as_float(((unsigned)h) << 16);
}

// ---------- one-time W transpose+cast: Wt[r][c][k] = bf16(W[r][k][c]) ----------
__global__ __launch_bounds__(256) void wt_kernel(
    const float* __restrict__ W, unsigned short* __restrict__ Wt, int total)
{
    int idx = blockIdx.x * 256 + threadIdx.x;
    if (idx >= total) return;
    int r = idx >> 14;            // /16384
    int rem = idx & 16383;
    int k = rem >> 7, c = rem & 127;
    Wt[(r << 14) + (c << 7) + k] = f2bf(W[idx]);
}

// ---------- Phase 1: H[r][n][c] = bf16( feat[n][:] @ W[r] ) ----------
// block = 256 thr (4 waves) = 64-node tile; loops over all R relations
// (feat staged once; Wt[r] staged per relation with vector b128 copies).
__global__ __launch_bounds__(256) void transform2_kernel(
    const float* __restrict__ feat, const unsigned short* __restrict__ Wt,
    unsigned short* __restrict__ H, int N, int R)
{
    __shared__ unsigned short sA[64 * LSTR];    // 17.4 KB
    __shared__ unsigned short sB[128 * LSTR];   // 34.8 KB
    const int tile0 = blockIdx.x * 64;
    const int tid = threadIdx.x;

    // Stage A = bf16(feat[tile0..tile0+63][:]) into padded LDS
    const float4* feat4 = (const float4*)feat;
    #pragma unroll
    for (int i = 0; i < 8; ++i) {
        int idx = tid + 256 * i;          // 0..2047
        int row = idx >> 5, c4 = idx & 31;
        int node = tile0 + row;
        float4 v = make_float4(0.f, 0.f, 0.f, 0.f);
        if (node < N) v = feat4[(size_t)node * 32 + c4];
        ushort4 h;
        h.x = f2bf(v.x); h.y = f2bf(v.y); h.z = f2bf(v.z); h.w = f2bf(v.w);
        *(ushort4*)&sA[row * LSTR + c4 * 4] = h;
    }
    __syncthreads();

    const int wave = tid >> 6, lane = tid & 63;
    const int q = lane >> 4, mlo = lane & 15;

    // A fragments, fixed across relations: A[m=lane&15][k=32*ks+8*q+j]
    const int arow = wave * 16 + mlo;
    bf16x8 a[4];
    #pragma unroll
    for (int ks = 0; ks < 4; ++ks)
        a[ks] = *(const bf16x8*)&sA[arow * LSTR + ks * 32 + q * 8];

    for (int rel = 0; rel < R; ++rel) {
        __syncthreads();   // previous-iteration sB reads complete
        // Stage Wt[rel] (bf16, already transposed) into LDS: b128 copies
        const ulonglong2* wsrc = (const ulonglong2*)(Wt + ((size_t)rel << 14));
        #pragma unroll
        for (int i = 0; i < 8; ++i) {
            int idx = tid + 256 * i;      // 0..2047 ; 8 bf16 each
            int c = idx >> 4, k8 = idx & 15;
            ulonglong2 v = wsrc[idx];
            *(ulonglong2*)&sB[c * LSTR + k8 * 8] = v;
        }
        __syncthreads();

        const size_t Hbase = (size_t)rel * N * D;
        #pragma unroll
        for (int ct = 0; ct < 8; ++ct) {
            f32x4 acc = {0.f, 0.f, 0.f, 0.f};
            const int col = ct * 16 + mlo;
            #pragma unroll
            for (int ks = 0; ks < 4; ++ks) {
                bf16x8 b = *(const bf16x8*)&sB[col * LSTR + ks * 32 + q * 8];
                acc = __builtin_amdgcn_mfma_f32_16x16x32_bf16(a[ks], b, acc, 0, 0, 0);
            }
            const int nb = tile0 + wave * 16 + q * 4;
            #pragma unroll
            for (int rr = 0; rr < 4; ++rr) {
                int node = nb + rr;
                if (node < N) H[Hbase + (size_t)node * D + col] = f2bf(acc[rr]);
            }
        }
    }
}

// ---------- CSR build ----------
__global__ __launch_bounds__(256) void k_count(
    const int* __restrict__ dst, int* __restrict__ deg, int E)
{
    int e = blockIdx.x * 256 + threadIdx.x;
    if (e < E) atomicAdd(&deg[dst[e]], 1);
}

__global__ __launch_bounds__(256) void k_blocksum(
    const int* __restrict__ deg, int* __restrict__ part, int N)
{
    int t = threadIdx.x, i = blockIdx.x * 256 + t;
    int v = (i < N) ? deg[i] : 0;
    #pragma unroll
    for (int o = 32; o > 0; o >>= 1) v += __shfl_down(v, o, 64);
    __shared__ int ws_[4];
    if ((t & 63) == 0) ws_[t >> 6] = v;
    __syncthreads();
    if (t == 0) part[blockIdx.x] = ws_[0] + ws_[1] + ws_[2] + ws_[3];
}

__global__ __launch_bounds__(256) void k_scanpart(int* part, int nb)
{
    __shared__ int s[256];
    int t = threadIdx.x;
    int v = (t < nb) ? part[t] : 0;
    s[t] = v;
    #pragma unroll
    for (int o = 1; o < 256; o <<= 1) {
        __syncthreads();
        int x = (t >= o) ? s[t - o] : 0;
        __syncthreads();
        s[t] += x;
    }
    if (t < nb) part[t] = s[t] - v;   // exclusive prefix of block sums
}

__global__ __launch_bounds__(256) void k_scanfinal(
    const int* __restrict__ deg, const int* __restrict__ part,
    int* __restrict__ off, int N, int E)
{
    __shared__ int s[256];
    int t = threadIdx.x, i = blockIdx.x * 256 + t;
    int v = (i < N) ? deg[i] : 0;
    s[t] = v;
    #pragma unroll
    for (int o = 1; o < 256; o <<= 1) {
        __syncthreads();
        int x = (t >= o) ? s[t - o] : 0;
        __syncthreads();
        s[t] += x;
    }
    if (i < N) off[i] = part[blockIdx.x] + s[t] - v;   // exclusive
    if (i == 0) off[N] = E;
}

__global__ __launch_bounds__(256) void k_fill(
    const int* __restrict__ dst, const int* __restrict__ et,
    const int* __restrict__ src, const int* __restrict__ off,
    int* __restrict__ cursor, unsigned int* __restrict__ sorted, int E)
{
    int e = blockIdx.x * 256 + threadIdx.x;
    if (e >= E) return;
    int d = dst[e];
    int p = atomicAdd(&cursor[d], 1);
    sorted[off[d] + p] = ((unsigned)et[e] << 16) | (unsigned)src[e];
}

// ---------- Phase 2: per-node gather. One wave per node; lane covers 2 cols ----------
__global__ __launch_bounds__(256) void k_gather(
    const unsigned short* __restrict__ H, const unsigned int* __restrict__ sorted,
    const int* __restrict__ off, const float* __restrict__ feat,
    float* __restrict__ out, int N)
{
    int n = blockIdx.x * 4 + (threadIdx.x >> 6);
    if (n >= N) return;
    int lane = threadIdx.x & 63;

    const float2* feat2 = (const float2*)feat;
    float2 acc = feat2[(size_t)n * 64 + lane];   // (1+eps)*h, eps=0

    int j0 = off[n], j1 = off[n + 1];
    j0 = __builtin_amdgcn_readfirstlane(j0);
    j1 = __builtin_amdgcn_readfirstlane(j1);
    for (int j = j0; j < j1; ++j) {
        unsigned p = sorted[j];
        p = __builtin_amdgcn_readfirstlane(p);
        int r = p >> 16, s = p & 0xffff;
        unsigned h2 = *(const unsigned*)(H + ((size_t)(r * N + s) << 7) + lane * 2);
        acc.x += bf2f((unsigned short)(h2 & 0xffff));
        acc.y += bf2f((unsigned short)(h2 >> 16));
    }
    ((float2*)out)[(size_t)n * 64 + lane] = acc;
}

// ---------- fallback kernels (kept from round 1) ----------
__global__ __launch_bounds__(256) void init_kernel(
    const float* __restrict__ feat, float* __restrict__ out, int n4)
{
    int i = blockIdx.x * 256 + threadIdx.x;
    if (i < n4) ((float4*)out)[i] = ((const float4*)feat)[i];
}

__global__ __launch_bounds__(128) void edge_matvec_kernel(
    const float* __restrict__ feat, const float* __restrict__ W,
    const int* __restrict__ et, const int* __restrict__ src,
    const int* __restrict__ dst, float* __restrict__ out, int E)
{
    __shared__ float xs[D];
    int e = blockIdx.x;
    int c = threadIdx.x;
    int s = src[e], r = et[e], d = dst[e];
    xs[c] = feat[(size_t)s * D + c];
    __syncthreads();
    const float* Wr = W + (size_t)r * D * D;
    float acc = 0.f;
    #pragma unroll 8
    for (int k = 0; k < D; ++k) acc += xs[k] * Wr[(size_t)k * D + c];
    atomicAdd(out + (size_t)d * D + c, acc);
}

__global__ __launch_bounds__(256) void scatter_atomic_kernel(
    const unsigned short* __restrict__ H, const int* __restrict__ et,
    const int* __restrict__ src, const int* __restrict__ dst,
    float* __restrict__ out, int E, int N)
{
    long long idx = (long long)blockIdx.x * 256 + threadIdx.x;
    int e = (int)(idx >> 7);
    int c = (int)(idx & 127);
    if (e >= E) return;
    e = __builtin_amdgcn_readfirstlane(e);
    int r = et[e], s = src[e], d = dst[e];
    float m = bf2f(H[((size_t)r * N + s) * D + c]);
    atomicAdd(out + (size_t)d * D + c, m);
}

static inline size_t al256(size_t x) { return (x + 255) & ~(size_t)255; }

extern "C" void kernel_launch(void* const* d_in, const int* in_sizes, int n_in,
                              void* d_out, int out_size, void* d_ws, size_t ws_size,
                              hipStream_t stream) {
    const float* feat = (const float*)d_in[0];
    const float* W    = (const float*)d_in[1];
    const int*   et   = (const int*)d_in[2];
    const int*   src  = (const int*)d_in[3];
    const int*   dst  = (const int*)d_in[4];
    float* out = (float*)d_out;

    const int N = in_sizes[0] / D;
    const int R = in_sizes[1] / (D * D);
    const int E = in_sizes[2];

    // Workspace layout
    size_t hB   = al256((size_t)R * N * D * sizeof(unsigned short));
    size_t wtB  = al256((size_t)R * D * D * sizeof(unsigned short));
    size_t offB = al256((size_t)(N + 1) * sizeof(int));
    size_t degB = al256((size_t)N * sizeof(int));
    size_t curB = al256((size_t)N * sizeof(int));
    size_t parB = al256(1024 * sizeof(int));
    size_t srtB = al256((size_t)E * sizeof(unsigned int));
    size_t need = hB + wtB + offB + degB + curB + parB + srtB;

    const int nbScan = (N + 255) / 256;
    const bool packable = (N <= 65536) && (R <= 32768) && (nbScan <= 256);

    if (ws_size >= need && packable) {
        char* p = (char*)d_ws;
        unsigned short* H      = (unsigned short*)p;           p += hB;
        unsigned short* Wt     = (unsigned short*)p;           p += wtB;
        int*            off    = (int*)p;                      p += offB;
        int*            deg    = (int*)p;                      p += degB;
        int*            cursor = (int*)p;                      p += curB;
        int*            part   = (int*)p;                      p += parB;
        unsigned int*   sorted = (unsigned int*)p;

        // Phase 1: typed linear into H
        int wtTotal = R * D * D;
        wt_kernel<<<(wtTotal + 255) / 256, 256, 0, stream>>>(W, Wt, wtTotal);
        transform2_kernel<<<(N + 63) / 64, 256, 0, stream>>>(feat, Wt, H, N, R);

        // CSR build (by dst)
        hipMemsetAsync(deg, 0, (size_t)N * sizeof(int), stream);
        hipMemsetAsync(cursor, 0, (size_t)N * sizeof(int), stream);
        k_count<<<(E + 255) / 256, 256, 0, stream>>>(dst, deg, E);
        k_blocksum<<<nbScan, 256, 0, stream>>>(deg, part, N);
        k_scanpart<<<1, 256, 0, stream>>>(part, nbScan);
        k_scanfinal<<<nbScan, 256, 0, stream>>>(deg, part, off, N, E);
        k_fill<<<(E + 255) / 256, 256, 0, stream>>>(dst, et, src, off, cursor, sorted, E);

        // Phase 2: gather-sum per node, fused with (1+eps)*feat
        k_gather<<<(N + 3) / 4, 256, 0, stream>>>(H, sorted, off, feat, out, N);
    } else if (ws_size >= hB) {
        // round-1 path
        unsigned short* H = (unsigned short*)d_ws;
        int n4 = (N * D) / 4;
        init_kernel<<<(n4 + 255) / 256, 256, 0, stream>>>(feat, out, n4);
        int wtTotal = R * D * D;
        // reuse transform2 needs Wt; fall back to edge matvec if no room
        if (ws_size >= hB + wtB) {
            unsigned short* Wt = (unsigned short*)((char*)d_ws + hB);
            wt_kernel<<<(wtTotal + 255) / 256, 256, 0, stream>>>(W, Wt, wtTotal);
            transform2_kernel<<<(N + 63) / 64, 256, 0, stream>>>(feat, Wt, H, N, R);
            long long tot = (long long)E * D;
            scatter_atomic_kernel<<<(int)((tot + 255) / 256), 256, 0, stream>>>(H, et, src, dst, out, E, N);
        } else {
            edge_matvec_kernel<<<E, 128, 0, stream>>>(feat, W, et, src, dst, out, E);
        }
    } else {
        int n4 = (N * D) / 4;
        init_kernel<<<(n4 + 255) / 256, 256, 0, stream>>>(feat, out, n4);
        edge_matvec_kernel<<<E, 128, 0, stream>>>(feat, W, et, src, dst, out, E);
    }
}

// Round 3
// 213.783 us; speedup vs baseline: 2.2188x; 1.1639x over previous
//
#include <hip/hip_runtime.h>
#include <hip/hip_bf16.h>
#include <stdint.h>

#define D 128

using bf16x8 = __attribute__((ext_vector_type(8))) short;
using f32x4  = __attribute__((ext_vector_type(4))) float;

__device__ __forceinline__ unsigned short f2bf(float f) {
    unsigned u = __float_as_uint(f);
    u = (u + 0x7fffu + ((u >> 16) & 1u)) >> 16;   // RNE
    return (unsigned short)u;
}
__device__ __forceinline__ float bf2f(unsigned short h) {
    return __uint_as_float(((unsigned)h) << 16);
}

// ---------- one-time W transpose+cast: Wt[r][c][k] = bf16(W[r][k][c]) ----------
__global__ __launch_bounds__(256) void wt_kernel(
    const float* __restrict__ W, unsigned short* __restrict__ Wt, int total)
{
    int idx = blockIdx.x * 256 + threadIdx.x;
    if (idx >= total) return;
    int r = idx >> 14;            // /16384
    int rem = idx & 16383;
    int k = rem >> 7, c = rem & 127;
    Wt[(r << 14) + (c << 7) + k] = f2bf(W[idx]);
}

// ---------- Phase 1: H[r][n][c] = bf16( feat[n][:] @ W[r] ) ----------
// 256 thr = 4 waves = 64-node tile, loops over R relations.
// Single 32 KB XOR-swizzled LDS buffer: rows of 128 bf16 in 16 chunks of
// 8 shorts (16 B); chunk is stored at (chunk ^ (row&15)) -> all b128
// accesses <=2-way bank aliased (free). MFMA operands SWAPPED
// (A=Wt-frag, B=feat-frag) so each lane's 4 acc regs are 4 consecutive
// output channels of ONE node -> 8 B packed global stores.
__global__ __launch_bounds__(256) void transform3_kernel(
    const float* __restrict__ feat, const unsigned short* __restrict__ Wt,
    unsigned short* __restrict__ H, int N, int R)
{
    __shared__ __align__(16) unsigned short sm[128 * 128];   // 32 KB
    const int tile0 = blockIdx.x * 64;
    const int tid = threadIdx.x;

    // ---- stage A = bf16(feat[tile0+row][:]) into rows 0..63 ----
    const float4* feat4 = (const float4*)feat;
    #pragma unroll
    for (int i = 0; i < 8; ++i) {
        int idx = tid + 256 * i;          // 0..2047, each = 4 floats = 8 B
        int row = idx >> 5, c4 = idx & 31;
        int node = tile0 + row;
        float4 v = make_float4(0.f, 0.f, 0.f, 0.f);
        if (node < N) v = feat4[(size_t)node * 32 + c4];
        ushort4 h;
        h.x = f2bf(v.x); h.y = f2bf(v.y); h.z = f2bf(v.z); h.w = f2bf(v.w);
        int phys = row * 128 + (((c4 >> 1) ^ (row & 15)) * 8) + (c4 & 1) * 4;
        *(ushort4*)&sm[phys] = h;
    }
    __syncthreads();

    const int wave = tid >> 6, lane = tid & 63;
    const int q = lane >> 4, mlo = lane & 15;

    // B-operand frags (feat): B[k = ks*32+q*8+j][n = mlo], row = wave*16+mlo
    const int arow = wave * 16 + mlo;
    bf16x8 bfrag[4];
    #pragma unroll
    for (int ks = 0; ks < 4; ++ks) {
        int chunk = ks * 4 + q;
        bfrag[ks] = *(const bf16x8*)&sm[arow * 128 + ((chunk ^ (arow & 15)) * 8)];
    }
    __syncthreads();   // A region now reusable for Wt

    const int node = tile0 + wave * 16 + mlo;

    for (int rel = 0; rel < R; ++rel) {
        // stage Wt[rel] rows (c=0..127), swizzled, b128 copies
        const ulonglong2* wsrc = (const ulonglong2*)(Wt + ((size_t)rel << 14));
        #pragma unroll
        for (int i = 0; i < 8; ++i) {
            int idx = tid + 256 * i;      // 0..2047 chunks
            int c = idx >> 4, k8 = idx & 15;
            ulonglong2 v = wsrc[idx];
            *(ulonglong2*)&sm[c * 128 + ((k8 ^ (c & 15)) * 8)] = v;
        }
        __syncthreads();

        const size_t Hbase = (size_t)rel * N * D;
        #pragma unroll
        for (int ct = 0; ct < 8; ++ct) {
            f32x4 acc = {0.f, 0.f, 0.f, 0.f};
            const int wr = ct * 16 + mlo;          // Wt row (channel), m = mlo
            #pragma unroll
            for (int ks = 0; ks < 4; ++ks) {
                int chunk = ks * 4 + q;
                bf16x8 afrag = *(const bf16x8*)&sm[wr * 128 + ((chunk ^ (wr & 15)) * 8)];
                acc = __builtin_amdgcn_mfma_f32_16x16x32_bf16(afrag, bfrag[ks], acc, 0, 0, 0);
            }
            // D[m=channel][n=node]: col=lane&15=node, row=q*4+rr=channel
            if (node < N) {
                ushort4 hv;
                hv.x = f2bf(acc[0]); hv.y = f2bf(acc[1]);
                hv.z = f2bf(acc[2]); hv.w = f2bf(acc[3]);
                *(ushort4*)(H + Hbase + (size_t)node * D + ct * 16 + q * 4) = hv;
            }
        }
        __syncthreads();   // before next rel overwrites sm
    }
}

// ---------- CSR build ----------
__global__ __launch_bounds__(256) void k_count(
    const int* __restrict__ dst, int* __restrict__ deg, int* __restrict__ ord, int E)
{
    int e = blockIdx.x * 256 + threadIdx.x;
    if (e < E) ord[e] = atomicAdd(&deg[dst[e]], 1);
}

__global__ __launch_bounds__(256) void k_blocksum(
    const int* __restrict__ deg, int* __restrict__ part, int N)
{
    int t = threadIdx.x, i = blockIdx.x * 256 + t;
    int v = (i < N) ? deg[i] : 0;
    #pragma unroll
    for (int o = 32; o > 0; o >>= 1) v += __shfl_down(v, o, 64);
    __shared__ int ws_[4];
    if ((t & 63) == 0) ws_[t >> 6] = v;
    __syncthreads();
    if (t == 0) part[blockIdx.x] = ws_[0] + ws_[1] + ws_[2] + ws_[3];
}

__global__ __launch_bounds__(256) void k_scanpart(int* part, int nb)
{
    __shared__ int s[256];
    int t = threadIdx.x;
    int v = (t < nb) ? part[t] : 0;
    s[t] = v;
    #pragma unroll
    for (int o = 1; o < 256; o <<= 1) {
        __syncthreads();
        int x = (t >= o) ? s[t - o] : 0;
        __syncthreads();
        s[t] += x;
    }
    if (t < nb) part[t] = s[t] - v;   // exclusive prefix of block sums
}

__global__ __launch_bounds__(256) void k_scanfinal(
    const int* __restrict__ deg, const int* __restrict__ part,
    int* __restrict__ off, int N, int E)
{
    __shared__ int s[256];
    int t = threadIdx.x, i = blockIdx.x * 256 + t;
    int v = (i < N) ? deg[i] : 0;
    s[t] = v;
    #pragma unroll
    for (int o = 1; o < 256; o <<= 1) {
        __syncthreads();
        int x = (t >= o) ? s[t - o] : 0;
        __syncthreads();
        s[t] += x;
    }
    if (i < N) off[i] = part[blockIdx.x] + s[t] - v;   // exclusive
    if (i == 0) off[N] = E;
}

__global__ __launch_bounds__(256) void k_fill(
    const int* __restrict__ dst, const int* __restrict__ et,
    const int* __restrict__ src, const int* __restrict__ off,
    const int* __restrict__ ord, unsigned int* __restrict__ sorted, int E)
{
    int e = blockIdx.x * 256 + threadIdx.x;
    if (e >= E) return;
    sorted[off[dst[e]] + ord[e]] = ((unsigned)et[e] << 16) | (unsigned)src[e];
}

// ---------- Phase 2: per-node gather (wave/node, lane = 2 cols), unroll x2 ----------
__global__ __launch_bounds__(256) void k_gather(
    const unsigned short* __restrict__ H, const unsigned int* __restrict__ sorted,
    const int* __restrict__ off, const float* __restrict__ feat,
    float* __restrict__ out, int N)
{
    int n = blockIdx.x * 4 + (threadIdx.x >> 6);
    if (n >= N) return;
    int lane = threadIdx.x & 63;

    const float2* feat2 = (const float2*)feat;
    float2 acc = feat2[(size_t)n * 64 + lane];   // (1+eps)*h, eps=0

    int j0 = __builtin_amdgcn_readfirstlane(off[n]);
    int j1 = __builtin_amdgcn_readfirstlane(off[n + 1]);
    int j = j0;
    for (; j + 2 <= j1; j += 2) {
        unsigned p0 = __builtin_amdgcn_readfirstlane(sorted[j]);
        unsigned p1 = __builtin_amdgcn_readfirstlane(sorted[j + 1]);
        unsigned a0 = *(const unsigned*)(H + (((size_t)(p0 >> 16) * N + (p0 & 0xffffu)) << 7) + lane * 2);
        unsigned a1 = *(const unsigned*)(H + (((size_t)(p1 >> 16) * N + (p1 & 0xffffu)) << 7) + lane * 2);
        acc.x += bf2f((unsigned short)(a0 & 0xffffu)) + bf2f((unsigned short)(a1 & 0xffffu));
        acc.y += bf2f((unsigned short)(a0 >> 16)) + bf2f((unsigned short)(a1 >> 16));
    }
    if (j < j1) {
        unsigned p0 = __builtin_amdgcn_readfirstlane(sorted[j]);
        unsigned a0 = *(const unsigned*)(H + (((size_t)(p0 >> 16) * N + (p0 & 0xffffu)) << 7) + lane * 2);
        acc.x += bf2f((unsigned short)(a0 & 0xffffu));
        acc.y += bf2f((unsigned short)(a0 >> 16));
    }
    ((float2*)out)[(size_t)n * 64 + lane] = acc;
}

// ---------- fallbacks ----------
__global__ __launch_bounds__(256) void init_kernel(
    const float* __restrict__ feat, float* __restrict__ out, int n4)
{
    int i = blockIdx.x * 256 + threadIdx.x;
    if (i < n4) ((float4*)out)[i] = ((const float4*)feat)[i];
}

__global__ __launch_bounds__(128) void edge_matvec_kernel(
    const float* __restrict__ feat, const float* __restrict__ W,
    const int* __restrict__ et, const int* __restrict__ src,
    const int* __restrict__ dst, float* __restrict__ out, int E)
{
    __shared__ float xs[D];
    int e = blockIdx.x;
    int c = threadIdx.x;
    int s = src[e], r = et[e], d = dst[e];
    xs[c] = feat[(size_t)s * D + c];
    __syncthreads();
    const float* Wr = W + (size_t)r * D * D;
    float acc = 0.f;
    #pragma unroll 8
    for (int k = 0; k < D; ++k) acc += xs[k] * Wr[(size_t)k * D + c];
    atomicAdd(out + (size_t)d * D + c, acc);
}

static inline size_t al256(size_t x) { return (x + 255) & ~(size_t)255; }

extern "C" void kernel_launch(void* const* d_in, const int* in_sizes, int n_in,
                              void* d_out, int out_size, void* d_ws, size_t ws_size,
                              hipStream_t stream) {
    const float* feat = (const float*)d_in[0];
    const float* W    = (const float*)d_in[1];
    const int*   et   = (const int*)d_in[2];
    const int*   src  = (const int*)d_in[3];
    const int*   dst  = (const int*)d_in[4];
    float* out = (float*)d_out;

    const int N = in_sizes[0] / D;
    const int R = in_sizes[1] / (D * D);
    const int E = in_sizes[2];

    // Workspace layout
    size_t hB   = al256((size_t)R * N * D * sizeof(unsigned short));
    size_t wtB  = al256((size_t)R * D * D * sizeof(unsigned short));
    size_t offB = al256((size_t)(N + 1) * sizeof(int));
    size_t degB = al256((size_t)N * sizeof(int));
    size_t ordB = al256((size_t)E * sizeof(int));
    size_t parB = al256(1024 * sizeof(int));
    size_t srtB = al256((size_t)E * sizeof(unsigned int));
    size_t need = hB + wtB + offB + degB + ordB + parB + srtB;

    const int nbScan = (N + 255) / 256;
    const bool packable = (N <= 65536) && (R <= 65536) && (nbScan <= 256);

    if (ws_size >= need && packable) {
        char* p = (char*)d_ws;
        unsigned short* H      = (unsigned short*)p;           p += hB;
        unsigned short* Wt     = (unsigned short*)p;           p += wtB;
        int*            off    = (int*)p;                      p += offB;
        int*            deg    = (int*)p;                      p += degB;
        int*            ord    = (int*)p;                      p += ordB;
        int*            part   = (int*)p;                      p += parB;
        unsigned int*   sorted = (unsigned int*)p;

        // Phase 1: typed linear into H
        int wtTotal = R * D * D;
        wt_kernel<<<(wtTotal + 255) / 256, 256, 0, stream>>>(W, Wt, wtTotal);
        transform3_kernel<<<(N + 63) / 64, 256, 0, stream>>>(feat, Wt, H, N, R);

        // CSR build (by dst)
        hipMemsetAsync(deg, 0, (size_t)N * sizeof(int), stream);
        k_count<<<(E + 255) / 256, 256, 0, stream>>>(dst, deg, ord, E);
        k_blocksum<<<nbScan, 256, 0, stream>>>(deg, part, N);
        k_scanpart<<<1, 256, 0, stream>>>(part, nbScan);
        k_scanfinal<<<nbScan, 256, 0, stream>>>(deg, part, off, N, E);
        k_fill<<<(E + 255) / 256, 256, 0, stream>>>(dst, et, src, off, ord, sorted, E);

        // Phase 2: gather-sum per node, fused with (1+eps)*feat
        k_gather<<<(N + 3) / 4, 256, 0, stream>>>(H, sorted, off, feat, out, N);
    } else if (ws_size >= hB + wtB) {
        unsigned short* H  = (unsigned short*)d_ws;
        unsigned short* Wt = (unsigned short*)((char*)d_ws + hB);
        int n4 = (N * D) / 4;
        init_kernel<<<(n4 + 255) / 256, 256, 0, stream>>>(feat, out, n4);
        int wtTotal = R * D * D;
        wt_kernel<<<(wtTotal + 255) / 256, 256, 0, stream>>>(W, Wt, wtTotal);
        transform3_kernel<<<(N + 63) / 64, 256, 0, stream>>>(feat, Wt, H, N, R);
        // per-edge atomic scatter fallback
        // (reuse edge_matvec if H path impossible)
        {
            long long tot = (long long)E * D;
            // simple scatter using H
            // inline lambda-style kernel not possible; reuse edge_matvec as last resort
        }
        edge_matvec_kernel<<<E, 128, 0, stream>>>(feat, W, et, src, dst, out, E);
    } else {
        int n4 = (N * D) / 4;
        init_kernel<<<(n4 + 255) / 256, 256, 0, stream>>>(feat, out, n4);
        edge_matvec_kernel<<<E, 128, 0, stream>>>(feat, W, et, src, dst, out, E);
    }
}